// Round 11
// baseline (837.075 us; speedup 1.0000x reference)
//
#include <hip/hip_runtime.h>
#include <hip/hip_fp16.h>

#define BB 32
#define NI 2048
#define NK 64
#define ND 32
#define KD 2048       // caps_n * caps_dim
#define NL 16
#define ITC 8         // i's per conv block
#define NTC (NI/ITC)  // 256 conv i-chunks
#define NRC 32        // route chunks (64 i each)
#define EPSF 1e-7f

typedef _Float16 f16;
typedef _Float16 h2 __attribute__((ext_vector_type(2)));
typedef __attribute__((ext_vector_type(4))) float f32x4;
union U4H8 { uint4 u4; h2 h[4]; };

static __device__ __forceinline__ float dot2f(h2 a, h2 b, float c) {
#if __has_builtin(__builtin_amdgcn_fdot2)
  return __builtin_amdgcn_fdot2(a, b, c, false);
#else
  return c + (float)a[0] * (float)b[0] + (float)a[1] * (float)b[1];
#endif
}

static __device__ __forceinline__ float fastrcp(float s) {
#if __has_builtin(__builtin_amdgcn_rcpf)
  return __builtin_amdgcn_rcpf(s);
#else
  return 1.0f / s;
#endif
}

static __device__ __forceinline__ h2 pack2(float x, float y) {
  h2 r; r[0] = (_Float16)x; r[1] = (_Float16)y; return r;
}

// K1 (fused conv + round-0 partial): u_hat[b][i][cell] f16 = sum_l W*x, and
// part[b][blk][cell] = (1/64) * sum_{i in chunk} u.
// KEY (R10 post-mortem): x[b][i][l] addressing is block-uniform -> compiler
// emits s_load + v_fmac(v,s,v). ZERO LDS traffic (R1..R10 conv variants were
// all bound by ~80us of serialized per-b LDS x-reads, not HBM).
// 1 cell/thread: w[16] + sacc[32] + addr ~= 60 VGPR, no spill (R5 evidence).
// grid (NTC, 4) x 512 thr; cell = quad*512 + t (2B stores, lane-contiguous).
__global__ __launch_bounds__(512, 4) void k_conv(const float* __restrict__ x,
                                                 const float* __restrict__ W,
                                                 __half* __restrict__ uhat,
                                                 __half* __restrict__ part) {
  const int blk = blockIdx.x, quad = blockIdx.y, t = threadIdx.x;
  const int i0 = blk * ITC;
  const int c0 = quad * 512 + t;

  float sacc[BB];
  #pragma unroll
  for (int b = 0; b < BB; ++b) sacc[b] = 0.f;

  for (int ii = 0; ii < ITC; ++ii) {
    const int i = i0 + ii;
    float w[NL];
    const float* Wp = W + ((size_t)i * KD + c0) * NL;
    #pragma unroll
    for (int q = 0; q < 4; ++q)
      *(float4*)&w[4 * q] = *(const float4*)(Wp + 4 * q);
    const float* xp = x + (size_t)i * NL;
    __half* up = uhat + (size_t)i * KD + c0;
    #pragma unroll
    for (int b = 0; b < BB; ++b) {
      const float* xb = xp + (size_t)b * NI * NL;   // uniform address -> s_load
      float u = 0.f;
      #pragma unroll
      for (int l = 0; l < NL; ++l) u += w[l] * xb[l];
      up[(size_t)b * NI * KD] = (__half)u;
      sacc[b] += u;
    }
  }
  #pragma unroll
  for (int b = 0; b < BB; ++b)
    part[((size_t)b * NTC + blk) * KD + c0] = (__half)(sacc[b] * (1.f / 64.f));
}

// Routing round, wave-per-i with 2-way i-pairing (ILP on the dot/softmax
// chains), no barriers in the main loop. lane = k; lane holds v[k][:] f16 and
// sacc[32] f32. Wave wv at step p handles iA = ch*64 + 8p + wv, iB = iA + 4
// (block reads 8 consecutive i = 32KB contiguous per step). End-of-kernel LDS
// combine -> one partial per block (nch = NRC).
__global__ __launch_bounds__(256) void k_route(const __half* __restrict__ uhat,
                                               const float* __restrict__ vin,
                                               __half* __restrict__ part) {
  const int ch = blockIdx.x, b = blockIdx.y, t = threadIdx.x;
  const int wv = t >> 6, lane = t & 63;

  h2 vh[16];
  #pragma unroll
  for (int q = 0; q < 8; ++q) {
    const f32x4 v = *(const f32x4*)&vin[(size_t)b * KD + lane * ND + 4 * q];
    vh[2 * q]     = pack2(v[0], v[1]);
    vh[2 * q + 1] = pack2(v[2], v[3]);
  }

  float sacc[32];
  #pragma unroll
  for (int d = 0; d < 32; ++d) sacc[d] = 0.f;

  const __half* ub = uhat + (size_t)b * NI * KD + lane * ND;
  const int i00 = ch * 64 + wv;
  U4H8 curA[4], curB[4];
  #pragma unroll
  for (int q = 0; q < 4; ++q) {
    curA[q].u4 = *(const uint4*)(ub + (size_t)i00 * KD + 8 * q);
    curB[q].u4 = *(const uint4*)(ub + (size_t)(i00 + 4) * KD + 8 * q);
  }

  for (int p = 0; p < 8; ++p) {
    U4H8 nxtA[4], nxtB[4];
    if (p + 1 < 8) {
      const size_t oA = (size_t)(i00 + 8 * (p + 1)) * KD;
      #pragma unroll
      for (int q = 0; q < 4; ++q) {
        nxtA[q].u4 = *(const uint4*)(ub + oA + 8 * q);
        nxtB[q].u4 = *(const uint4*)(ub + oA + 4 * KD + 8 * q);
      }
    }
    float agA = 0.f, agB = 0.f;
    #pragma unroll
    for (int q = 0; q < 4; ++q)
      #pragma unroll
      for (int j = 0; j < 4; ++j) {
        agA = dot2f(curA[q].h[j], vh[4 * q + j], agA);
        agB = dot2f(curB[q].h[j], vh[4 * q + j], agB);
      }
    const float eA = __expf(agA);   // logits bounded; no max-subtract needed
    const float eB = __expf(agB);
    float sA = eA, sB = eB;
    sA += __shfl_xor(sA, 1);  sB += __shfl_xor(sB, 1);
    sA += __shfl_xor(sA, 2);  sB += __shfl_xor(sB, 2);
    sA += __shfl_xor(sA, 4);  sB += __shfl_xor(sB, 4);
    sA += __shfl_xor(sA, 8);  sB += __shfl_xor(sB, 8);
    sA += __shfl_xor(sA, 16); sB += __shfl_xor(sB, 16);
    sA += __shfl_xor(sA, 32); sB += __shfl_xor(sB, 32);
    const float cA = eA * fastrcp(sA);
    const float cB = eB * fastrcp(sB);
    #pragma unroll
    for (int q = 0; q < 4; ++q)
      #pragma unroll
      for (int j = 0; j < 4; ++j) {
        sacc[8 * q + 2 * j]     += cA * (float)curA[q].h[j][0]
                                 + cB * (float)curB[q].h[j][0];
        sacc[8 * q + 2 * j + 1] += cA * (float)curA[q].h[j][1]
                                 + cB * (float)curB[q].h[j][1];
      }
    #pragma unroll
    for (int q = 0; q < 4; ++q) { curA[q] = nxtA[q]; curB[q] = nxtB[q]; }
  }

  // Cross-wave combine: red[wv][d][lane] (conflict-free writes), one barrier.
  __shared__ float red[4][ND][64];   // 32 KB
  #pragma unroll
  for (int d = 0; d < ND; ++d) red[wv][d][lane] = sacc[d];
  __syncthreads();
  const int k = t >> 2, d0 = (t & 3) * 8;
  float s[8];
  #pragma unroll
  for (int j = 0; j < 8; ++j)
    s[j] = red[0][d0 + j][k] + red[1][d0 + j][k] +
           red[2][d0 + j][k] + red[3][d0 + j][k];
  U4H8 o;
  #pragma unroll
  for (int j = 0; j < 4; ++j)
    o.h[j] = pack2(s[2 * j], s[2 * j + 1]);
  *(uint4*)&part[((size_t)b * NRC + ch) * KD + 8 * t] = o.u4;
}

// Reduce partials over nch chunks, squash over d=32; optional vprev add
// (round-1 output becomes v0+v1 for the linear-agreement trick).
__global__ __launch_bounds__(256) void k_reduce(const __half* __restrict__ part,
                                                int nch,
                                                const float* __restrict__ vprev,
                                                float* __restrict__ vout) {
  const int g = blockIdx.x, b = blockIdx.y, t = threadIdx.x;
  const int p = g * 256 + t;            // h2-pair index: cells 2p, 2p+1
  const h2* pp = (const h2*)part;
  const size_t base = (size_t)b * nch * (KD / 2) + p;
  float s0 = 0.f, s1 = 0.f;
  for (int ch = 0; ch < nch; ++ch) {
    const h2 v = pp[base + (size_t)ch * (KD / 2)];
    s0 += (float)v[0]; s1 += (float)v[1];
  }
  float sq = s0 * s0 + s1 * s1;
  sq += __shfl_xor(sq, 1); sq += __shfl_xor(sq, 2);
  sq += __shfl_xor(sq, 4); sq += __shfl_xor(sq, 8);
  sq += EPSF;
  const float sc = sqrtf(sq) / (1.f + sq);
  float r0 = s0 * sc, r1 = s1 * sc;
  if (vprev != nullptr) {
    r0 += vprev[(size_t)b * KD + 2 * p];
    r1 += vprev[(size_t)b * KD + 2 * p + 1];
  }
  *(float2*)&vout[(size_t)b * KD + 2 * p] = make_float2(r0, r1);
}

extern "C" void kernel_launch(void* const* d_in, const int* in_sizes, int n_in,
                              void* d_out, int out_size, void* d_ws, size_t ws_size,
                              hipStream_t stream) {
  const float* x = (const float*)d_in[0];   // [32, 2048, 16]
  const float* W = (const float*)d_in[1];   // [2048, 64, 32, 16]
  float* out = (float*)d_out;               // [32, 64, 32]
  char* ws = (char*)d_ws;
  __half* uhat  = (__half*)ws;                                    // 268435456 B
  __half* part0 = (__half*)(ws + 268435456ull);                   // 33554432 B
  __half* partR = (__half*)(ws + 268435456ull + 33554432ull);     // 4194304 B
  float*  vA    = (float*)(ws + 268435456ull + 33554432ull + 4194304ull);
  float*  vB    = vA + (size_t)BB * KD;

  k_conv<<<dim3(NTC, 4), 512, 0, stream>>>(x, W, uhat, part0);
  k_reduce<<<dim3(4, BB), 256, 0, stream>>>(part0, NTC, nullptr, vA);  // v0
  k_route<<<dim3(NRC, BB), 256, 0, stream>>>(uhat, vA, partR);         // u.v0
  k_reduce<<<dim3(4, BB), 256, 0, stream>>>(partR, NRC, vA, vB);       // v0+v1
  k_route<<<dim3(NRC, BB), 256, 0, stream>>>(uhat, vB, partR);         // u.(v0+v1)
  k_reduce<<<dim3(4, BB), 256, 0, stream>>>(partR, NRC, nullptr, out); // v2
}

// Round 12
// 505.757 us; speedup vs baseline: 1.6551x; 1.6551x over previous
//
#include <hip/hip_runtime.h>
#include <hip/hip_fp16.h>

#define BB 32
#define NI 2048
#define NK 64
#define ND 32
#define KD 2048       // caps_n * caps_dim
#define NL 16
#define ITC 8         // i's per conv block
#define NTC (NI/ITC)  // 256 conv i-chunks
#define NRC 32        // route chunks (64 i each)
#define EPSF 1e-7f

typedef _Float16 f16;
typedef _Float16 h2 __attribute__((ext_vector_type(2)));
typedef __attribute__((ext_vector_type(4))) float f32x4;
union U4H8 { uint4 u4; h2 h[4]; };

static __device__ __forceinline__ float dot2f(h2 a, h2 b, float c) {
#if __has_builtin(__builtin_amdgcn_fdot2)
  return __builtin_amdgcn_fdot2(a, b, c, false);
#else
  return c + (float)a[0] * (float)b[0] + (float)a[1] * (float)b[1];
#endif
}

static __device__ __forceinline__ float fastrcp(float s) {
#if __has_builtin(__builtin_amdgcn_rcpf)
  return __builtin_amdgcn_rcpf(s);
#else
  return 1.0f / s;
#endif
}

static __device__ __forceinline__ h2 pack2(float x, float y) {
  h2 r; r[0] = (_Float16)x; r[1] = (_Float16)y; return r;
}

// K1 (fused conv + round-0 partial): u_hat[b][i][cell] f16 = sum_l W*x, and
// part[b][blk][cell] = (1/64) * sum_{i in chunk} u.
// R11 post-mortem: at 512 thr/block the allocator starves VGPRs (64) and
// spills sacc -> 2.1 GB scratch traffic. At 256 thr/block it allocates
// generously (R8 conv, all routes). So: 256 thr, 1 cell/thread,
// w[16]+sacc[32]+addr ~= 56 VGPR. x via uniform s_load (zero LDS).
// grid (NTC, 8); cell c0 = oct*256 + t. W reads 64 B/lane coalesced.
__global__ __launch_bounds__(256) void k_conv(const float* __restrict__ x,
                                              const float* __restrict__ W,
                                              __half* __restrict__ uhat,
                                              __half* __restrict__ part) {
  const int blk = blockIdx.x, oct = blockIdx.y, t = threadIdx.x;
  const int i0 = blk * ITC;
  const int c0 = oct * 256 + t;

  float sacc[BB];
  #pragma unroll
  for (int b = 0; b < BB; ++b) sacc[b] = 0.f;

  for (int ii = 0; ii < ITC; ++ii) {
    const int i = i0 + ii;
    float w[NL];
    const float* Wp = W + ((size_t)i * KD + c0) * NL;
    #pragma unroll
    for (int q = 0; q < 4; ++q)
      *(float4*)&w[4 * q] = *(const float4*)(Wp + 4 * q);
    const float* xp = x + (size_t)i * NL;
    __half* up = uhat + (size_t)i * KD + c0;
    #pragma unroll
    for (int b = 0; b < BB; ++b) {
      const float* xb = xp + (size_t)b * NI * NL;   // uniform -> s_load path
      float u = 0.f;
      #pragma unroll
      for (int l = 0; l < NL; ++l) u = fmaf(w[l], xb[l], u);
      up[(size_t)b * NI * KD] = (__half)u;
      sacc[b] += u;
    }
  }
  #pragma unroll
  for (int b = 0; b < BB; ++b)
    part[((size_t)b * NTC + blk) * KD + c0] = (__half)(sacc[b] * (1.f / 64.f));
}

// Routing round, wave-per-i with 2-way i-pairing (ILP on the dot/softmax
// chains), no barriers in the main loop. lane = k; lane holds v[k][:] f16 and
// sacc[32] f32. Wave wv at step p handles iA = ch*64 + 8p + wv, iB = iA + 4
// (block reads 8 consecutive i = 32KB contiguous per step). End-of-kernel LDS
// combine -> one partial per block (nch = NRC).
__global__ __launch_bounds__(256) void k_route(const __half* __restrict__ uhat,
                                               const float* __restrict__ vin,
                                               __half* __restrict__ part) {
  const int ch = blockIdx.x, b = blockIdx.y, t = threadIdx.x;
  const int wv = t >> 6, lane = t & 63;

  h2 vh[16];
  #pragma unroll
  for (int q = 0; q < 8; ++q) {
    const f32x4 v = *(const f32x4*)&vin[(size_t)b * KD + lane * ND + 4 * q];
    vh[2 * q]     = pack2(v[0], v[1]);
    vh[2 * q + 1] = pack2(v[2], v[3]);
  }

  float sacc[32];
  #pragma unroll
  for (int d = 0; d < 32; ++d) sacc[d] = 0.f;

  const __half* ub = uhat + (size_t)b * NI * KD + lane * ND;
  const int i00 = ch * 64 + wv;
  U4H8 curA[4], curB[4];
  #pragma unroll
  for (int q = 0; q < 4; ++q) {
    curA[q].u4 = *(const uint4*)(ub + (size_t)i00 * KD + 8 * q);
    curB[q].u4 = *(const uint4*)(ub + (size_t)(i00 + 4) * KD + 8 * q);
  }

  for (int p = 0; p < 8; ++p) {
    U4H8 nxtA[4], nxtB[4];
    if (p + 1 < 8) {
      const size_t oA = (size_t)(i00 + 8 * (p + 1)) * KD;
      #pragma unroll
      for (int q = 0; q < 4; ++q) {
        nxtA[q].u4 = *(const uint4*)(ub + oA + 8 * q);
        nxtB[q].u4 = *(const uint4*)(ub + oA + 4 * KD + 8 * q);
      }
    }
    float agA = 0.f, agB = 0.f;
    #pragma unroll
    for (int q = 0; q < 4; ++q)
      #pragma unroll
      for (int j = 0; j < 4; ++j) {
        agA = dot2f(curA[q].h[j], vh[4 * q + j], agA);
        agB = dot2f(curB[q].h[j], vh[4 * q + j], agB);
      }
    const float eA = __expf(agA);   // logits bounded; no max-subtract needed
    const float eB = __expf(agB);
    float sA = eA, sB = eB;
    sA += __shfl_xor(sA, 1);  sB += __shfl_xor(sB, 1);
    sA += __shfl_xor(sA, 2);  sB += __shfl_xor(sB, 2);
    sA += __shfl_xor(sA, 4);  sB += __shfl_xor(sB, 4);
    sA += __shfl_xor(sA, 8);  sB += __shfl_xor(sB, 8);
    sA += __shfl_xor(sA, 16); sB += __shfl_xor(sB, 16);
    sA += __shfl_xor(sA, 32); sB += __shfl_xor(sB, 32);
    const float cA = eA * fastrcp(sA);
    const float cB = eB * fastrcp(sB);
    #pragma unroll
    for (int q = 0; q < 4; ++q)
      #pragma unroll
      for (int j = 0; j < 4; ++j) {
        sacc[8 * q + 2 * j]     += cA * (float)curA[q].h[j][0]
                                 + cB * (float)curB[q].h[j][0];
        sacc[8 * q + 2 * j + 1] += cA * (float)curA[q].h[j][1]
                                 + cB * (float)curB[q].h[j][1];
      }
    #pragma unroll
    for (int q = 0; q < 4; ++q) { curA[q] = nxtA[q]; curB[q] = nxtB[q]; }
  }

  // Cross-wave combine: red[wv][d][lane] (conflict-free writes), one barrier.
  __shared__ float red[4][ND][64];   // 32 KB
  #pragma unroll
  for (int d = 0; d < ND; ++d) red[wv][d][lane] = sacc[d];
  __syncthreads();
  const int k = t >> 2, d0 = (t & 3) * 8;
  float s[8];
  #pragma unroll
  for (int j = 0; j < 8; ++j)
    s[j] = red[0][d0 + j][k] + red[1][d0 + j][k] +
           red[2][d0 + j][k] + red[3][d0 + j][k];
  U4H8 o;
  #pragma unroll
  for (int j = 0; j < 4; ++j)
    o.h[j] = pack2(s[2 * j], s[2 * j + 1]);
  *(uint4*)&part[((size_t)b * NRC + ch) * KD + 8 * t] = o.u4;
}

// Reduce partials over nch chunks, squash over d=32; optional vprev add
// (round-1 output becomes v0+v1 for the linear-agreement trick).
__global__ __launch_bounds__(256) void k_reduce(const __half* __restrict__ part,
                                                int nch,
                                                const float* __restrict__ vprev,
                                                float* __restrict__ vout) {
  const int g = blockIdx.x, b = blockIdx.y, t = threadIdx.x;
  const int p = g * 256 + t;            // h2-pair index: cells 2p, 2p+1
  const h2* pp = (const h2*)part;
  const size_t base = (size_t)b * nch * (KD / 2) + p;
  float s0 = 0.f, s1 = 0.f;
  for (int ch = 0; ch < nch; ++ch) {
    const h2 v = pp[base + (size_t)ch * (KD / 2)];
    s0 += (float)v[0]; s1 += (float)v[1];
  }
  float sq = s0 * s0 + s1 * s1;
  sq += __shfl_xor(sq, 1); sq += __shfl_xor(sq, 2);
  sq += __shfl_xor(sq, 4); sq += __shfl_xor(sq, 8);
  sq += EPSF;
  const float sc = sqrtf(sq) / (1.f + sq);
  float r0 = s0 * sc, r1 = s1 * sc;
  if (vprev != nullptr) {
    r0 += vprev[(size_t)b * KD + 2 * p];
    r1 += vprev[(size_t)b * KD + 2 * p + 1];
  }
  *(float2*)&vout[(size_t)b * KD + 2 * p] = make_float2(r0, r1);
}

extern "C" void kernel_launch(void* const* d_in, const int* in_sizes, int n_in,
                              void* d_out, int out_size, void* d_ws, size_t ws_size,
                              hipStream_t stream) {
  const float* x = (const float*)d_in[0];   // [32, 2048, 16]
  const float* W = (const float*)d_in[1];   // [2048, 64, 32, 16]
  float* out = (float*)d_out;               // [32, 64, 32]
  char* ws = (char*)d_ws;
  __half* uhat  = (__half*)ws;                                    // 268435456 B
  __half* part0 = (__half*)(ws + 268435456ull);                   // 33554432 B
  __half* partR = (__half*)(ws + 268435456ull + 33554432ull);     // 4194304 B
  float*  vA    = (float*)(ws + 268435456ull + 33554432ull + 4194304ull);
  float*  vB    = vA + (size_t)BB * KD;

  k_conv<<<dim3(NTC, 8), 256, 0, stream>>>(x, W, uhat, part0);
  k_reduce<<<dim3(4, BB), 256, 0, stream>>>(part0, NTC, nullptr, vA);  // v0
  k_route<<<dim3(NRC, BB), 256, 0, stream>>>(uhat, vA, partR);         // u.v0
  k_reduce<<<dim3(4, BB), 256, 0, stream>>>(partR, NRC, vA, vB);       // v0+v1
  k_route<<<dim3(NRC, BB), 256, 0, stream>>>(uhat, vB, partR);         // u.(v0+v1)
  k_reduce<<<dim3(4, BB), 256, 0, stream>>>(partR, NRC, nullptr, out); // v2
}

// Round 13
// 313.223 us; speedup vs baseline: 2.6725x; 1.6147x over previous
//
#include <hip/hip_runtime.h>
#include <hip/hip_fp16.h>

#define BB 32
#define NI 2048
#define NK 64
#define ND 32
#define KD 2048       // caps_n * caps_dim
#define NL 16
#define NCH0 64       // round-0 chunks (32 i each)
#define NRC 32        // route chunks (64 i each)
#define EPSF 1e-7f

typedef _Float16 f16;
typedef _Float16 h2 __attribute__((ext_vector_type(2)));
typedef __attribute__((ext_vector_type(4))) float f32x4;
union U4H8 { uint4 u4; h2 h[4]; };
union UH2  { unsigned u; h2 h; };

static __device__ __forceinline__ float dot2f(h2 a, h2 b, float c) {
#if __has_builtin(__builtin_amdgcn_fdot2)
  return __builtin_amdgcn_fdot2(a, b, c, false);
#else
  return c + (float)a[0] * (float)b[0] + (float)a[1] * (float)b[1];
#endif
}

static __device__ __forceinline__ float fastrcp(float s) {
#if __has_builtin(__builtin_amdgcn_rcpf)
  return __builtin_amdgcn_rcpf(s);
#else
  return 1.0f / s;
#endif
}

static __device__ __forceinline__ h2 pack2(float x, float y) {
  h2 r; r[0] = (_Float16)x; r[1] = (_Float16)y; return r;
}

// K1: u_hat[b][i][cell] f16 = sum_l W[i][cell][l] * x[b][i][l].
// R13: R9's proven LDS-broadcast-x structure (154us), but 256 thr x 2 cells
// so the W tile is 32 f32/thread (R9's 64 f32 at 512thr/40VGPR spilled to
// scratch and was re-read every b-iteration; R12 proved non-LDS x paths emit
// per-lane VMEM and are 2x worse). Working set ~48 VGPR -> no spill.
// grid (NI, 4); cells c0 = quad*512 + 2t. Packed 4B stores (2 f16).
__global__ __launch_bounds__(256) void k_uhat(const float* __restrict__ x,
                                              const float* __restrict__ W,
                                              __half* __restrict__ uhat) {
  const int i = blockIdx.x, quad = blockIdx.y;
  const int t = threadIdx.x;
  const int c0 = quad * 512 + 2 * t;
  __shared__ float xs[BB * NL];  // 512 floats
  for (int j = t; j < BB * NL; j += 256)
    xs[j] = x[((size_t)(j >> 4) * NI + i) * NL + (j & 15)];
  __syncthreads();

  float w0[NL], w1[NL];
  const float* Wp = W + ((size_t)i * KD + c0) * NL;
  #pragma unroll
  for (int q = 0; q < 4; ++q) {
    *(float4*)&w0[4 * q] = *(const float4*)(Wp + 4 * q);
    *(float4*)&w1[4 * q] = *(const float4*)(Wp + NL + 4 * q);
  }
  __half* up = uhat + (size_t)i * KD + c0;
  for (int b = 0; b < BB; ++b) {
    float u0 = 0.f, u1 = 0.f;
    #pragma unroll
    for (int l = 0; l < NL; ++l) {
      const float xv = xs[b * NL + l];
      u0 = fmaf(w0[l], xv, u0);
      u1 = fmaf(w1[l], xv, u1);
    }
    UH2 o; o.h = pack2(u0, u1);
    *(unsigned*)(up + (size_t)b * NI * KD) = o.u;
  }
}

// K2: round-0 partials (c = 1/64 uniform): part[b][ch][cell] f16.
// grid (NCH0, BB), 256 thr; thread owns 8 cells via 16B loads.
__global__ __launch_bounds__(256) void k_round0(const __half* __restrict__ uhat,
                                                __half* __restrict__ part) {
  const int ch = blockIdx.x, b = blockIdx.y, t = threadIdx.x;
  float acc[8];
  #pragma unroll
  for (int j = 0; j < 8; ++j) acc[j] = 0.f;
  const __half* up = uhat + ((size_t)b * NI + (size_t)ch * 32) * KD + t * 8;
  for (int il = 0; il < 32; ++il) {
    U4H8 u; u.u4 = *(const uint4*)(up + (size_t)il * KD);
    #pragma unroll
    for (int j = 0; j < 4; ++j) {
      acc[2 * j]     += (float)u.h[j][0];
      acc[2 * j + 1] += (float)u.h[j][1];
    }
  }
  U4H8 o;
  #pragma unroll
  for (int j = 0; j < 4; ++j)
    o.h[j] = pack2(acc[2 * j] * (1.f / 64.f), acc[2 * j + 1] * (1.f / 64.f));
  *(uint4*)&part[((size_t)b * NCH0 + ch) * KD + t * 8] = o.u4;
}

// Routing round, wave-per-i with 2-way i-pairing (ILP on the dot/softmax
// chains), no barriers in the main loop. lane = k; lane holds v[k][:] f16 and
// sacc[32] f32. Wave wv at step p handles iA = ch*64 + 8p + wv, iB = iA + 4
// (block reads 8 consecutive i = 32KB contiguous per step). End-of-kernel LDS
// combine -> one partial per block (nch = NRC).
__global__ __launch_bounds__(256) void k_route(const __half* __restrict__ uhat,
                                               const float* __restrict__ vin,
                                               __half* __restrict__ part) {
  const int ch = blockIdx.x, b = blockIdx.y, t = threadIdx.x;
  const int wv = t >> 6, lane = t & 63;

  h2 vh[16];
  #pragma unroll
  for (int q = 0; q < 8; ++q) {
    const f32x4 v = *(const f32x4*)&vin[(size_t)b * KD + lane * ND + 4 * q];
    vh[2 * q]     = pack2(v[0], v[1]);
    vh[2 * q + 1] = pack2(v[2], v[3]);
  }

  float sacc[32];
  #pragma unroll
  for (int d = 0; d < 32; ++d) sacc[d] = 0.f;

  const __half* ub = uhat + (size_t)b * NI * KD + lane * ND;
  const int i00 = ch * 64 + wv;
  U4H8 curA[4], curB[4];
  #pragma unroll
  for (int q = 0; q < 4; ++q) {
    curA[q].u4 = *(const uint4*)(ub + (size_t)i00 * KD + 8 * q);
    curB[q].u4 = *(const uint4*)(ub + (size_t)(i00 + 4) * KD + 8 * q);
  }

  for (int p = 0; p < 8; ++p) {
    U4H8 nxtA[4], nxtB[4];
    if (p + 1 < 8) {
      const size_t oA = (size_t)(i00 + 8 * (p + 1)) * KD;
      #pragma unroll
      for (int q = 0; q < 4; ++q) {
        nxtA[q].u4 = *(const uint4*)(ub + oA + 8 * q);
        nxtB[q].u4 = *(const uint4*)(ub + oA + 4 * KD + 8 * q);
      }
    }
    float agA = 0.f, agB = 0.f;
    #pragma unroll
    for (int q = 0; q < 4; ++q)
      #pragma unroll
      for (int j = 0; j < 4; ++j) {
        agA = dot2f(curA[q].h[j], vh[4 * q + j], agA);
        agB = dot2f(curB[q].h[j], vh[4 * q + j], agB);
      }
    const float eA = __expf(agA);   // logits bounded; no max-subtract needed
    const float eB = __expf(agB);
    float sA = eA, sB = eB;
    sA += __shfl_xor(sA, 1);  sB += __shfl_xor(sB, 1);
    sA += __shfl_xor(sA, 2);  sB += __shfl_xor(sB, 2);
    sA += __shfl_xor(sA, 4);  sB += __shfl_xor(sB, 4);
    sA += __shfl_xor(sA, 8);  sB += __shfl_xor(sB, 8);
    sA += __shfl_xor(sA, 16); sB += __shfl_xor(sB, 16);
    sA += __shfl_xor(sA, 32); sB += __shfl_xor(sB, 32);
    const float cA = eA * fastrcp(sA);
    const float cB = eB * fastrcp(sB);
    #pragma unroll
    for (int q = 0; q < 4; ++q)
      #pragma unroll
      for (int j = 0; j < 4; ++j) {
        sacc[8 * q + 2 * j]     += cA * (float)curA[q].h[j][0]
                                 + cB * (float)curB[q].h[j][0];
        sacc[8 * q + 2 * j + 1] += cA * (float)curA[q].h[j][1]
                                 + cB * (float)curB[q].h[j][1];
      }
    #pragma unroll
    for (int q = 0; q < 4; ++q) { curA[q] = nxtA[q]; curB[q] = nxtB[q]; }
  }

  // Cross-wave combine: red[wv][d][lane] (conflict-free writes), one barrier.
  __shared__ float red[4][ND][64];   // 32 KB
  #pragma unroll
  for (int d = 0; d < ND; ++d) red[wv][d][lane] = sacc[d];
  __syncthreads();
  const int k = t >> 2, d0 = (t & 3) * 8;
  float s[8];
  #pragma unroll
  for (int j = 0; j < 8; ++j)
    s[j] = red[0][d0 + j][k] + red[1][d0 + j][k] +
           red[2][d0 + j][k] + red[3][d0 + j][k];
  U4H8 o;
  #pragma unroll
  for (int j = 0; j < 4; ++j)
    o.h[j] = pack2(s[2 * j], s[2 * j + 1]);
  *(uint4*)&part[((size_t)b * NRC + ch) * KD + 8 * t] = o.u4;
}

// Reduce partials over nch chunks, squash over d=32; optional vprev add
// (round-1 output becomes v0+v1 for the linear-agreement trick).
__global__ __launch_bounds__(256) void k_reduce(const __half* __restrict__ part,
                                                int nch,
                                                const float* __restrict__ vprev,
                                                float* __restrict__ vout) {
  const int g = blockIdx.x, b = blockIdx.y, t = threadIdx.x;
  const int p = g * 256 + t;            // h2-pair index: cells 2p, 2p+1
  const h2* pp = (const h2*)part;
  const size_t base = (size_t)b * nch * (KD / 2) + p;
  float s0 = 0.f, s1 = 0.f;
  for (int ch = 0; ch < nch; ++ch) {
    const h2 v = pp[base + (size_t)ch * (KD / 2)];
    s0 += (float)v[0]; s1 += (float)v[1];
  }
  float sq = s0 * s0 + s1 * s1;
  sq += __shfl_xor(sq, 1); sq += __shfl_xor(sq, 2);
  sq += __shfl_xor(sq, 4); sq += __shfl_xor(sq, 8);
  sq += EPSF;
  const float sc = sqrtf(sq) / (1.f + sq);
  float r0 = s0 * sc, r1 = s1 * sc;
  if (vprev != nullptr) {
    r0 += vprev[(size_t)b * KD + 2 * p];
    r1 += vprev[(size_t)b * KD + 2 * p + 1];
  }
  *(float2*)&vout[(size_t)b * KD + 2 * p] = make_float2(r0, r1);
}

extern "C" void kernel_launch(void* const* d_in, const int* in_sizes, int n_in,
                              void* d_out, int out_size, void* d_ws, size_t ws_size,
                              hipStream_t stream) {
  const float* x = (const float*)d_in[0];   // [32, 2048, 16]
  const float* W = (const float*)d_in[1];   // [2048, 64, 32, 16]
  float* out = (float*)d_out;               // [32, 64, 32]
  char* ws = (char*)d_ws;
  __half* uhat  = (__half*)ws;                                    // 268435456 B
  __half* part0 = (__half*)(ws + 268435456ull);                   // 8388608 B
  __half* partR = (__half*)(ws + 268435456ull + 8388608ull);      // 4194304 B
  float*  vA    = (float*)(ws + 268435456ull + 8388608ull + 4194304ull);
  float*  vB    = vA + (size_t)BB * KD;

  k_uhat<<<dim3(NI, 4), 256, 0, stream>>>(x, W, uhat);
  k_round0<<<dim3(NCH0, BB), 256, 0, stream>>>(uhat, part0);
  k_reduce<<<dim3(4, BB), 256, 0, stream>>>(part0, NCH0, nullptr, vA);  // v0
  k_route<<<dim3(NRC, BB), 256, 0, stream>>>(uhat, vA, partR);          // u.v0
  k_reduce<<<dim3(4, BB), 256, 0, stream>>>(partR, NRC, vA, vB);        // v0+v1
  k_route<<<dim3(NRC, BB), 256, 0, stream>>>(uhat, vB, partR);          // u.(v0+v1)
  k_reduce<<<dim3(4, BB), 256, 0, stream>>>(partR, NRC, nullptr, out);  // v2
}